// Round 7
// baseline (607.059 us; speedup 1.0000x reference)
//
#include <hip/hip_runtime.h>

#define N_COARSE_C 250000
#define KNB 9
#define CIN 64
#define COUT 64
#define NKK 18            // K = 576 = 18 * 32
#define G_TILES 4         // 128-row tiles per block
#define ROWS_PER_BLOCK 512

typedef __attribute__((ext_vector_type(8))) short short8;
typedef __attribute__((ext_vector_type(4))) float f32x4;

__device__ __forceinline__ unsigned short f2bf(float x) {
    __bf16 h = (__bf16)x;                 // fptrunc = RNE; pairs fuse to v_cvt_pk_bf16_f32
    return __builtin_bit_cast(unsigned short, h);
}

// 512 threads = 8 waves. Each block processes 4 tiles of 128 coarse rows
// (wave w owns rows [tile_c0 + w*16, +16)). MFMA 16x16x32 bf16, fp32 accum.
// Gather loads are software-pipelined depth-4 (16 x 16B loads in flight per
// lane) to hide L2/L3/HBM latency. W staged once per block (amortized over
// 512 rows) with vectorized loads, LDS in B-fragment order -> hot-loop
// ds_read_b128 is contiguous & conflict-free.
__global__ __launch_bounds__(512, 4) void relu_coarsen_mfma(
    const float* __restrict__ lv,      // [1e6][64] f32
    const int*   __restrict__ nbr,     // [250000][9] int32
    const float* __restrict__ W,       // [576][64] f32
    const float* __restrict__ bias,    // [64] f32
    float*       __restrict__ out)     // [250000][64] f32
{
    __shared__ short wf[NKK * 4 * 64 * 8];  // 36864 bf16 = 73728 B -> 2 blocks/CU

    const int tid = threadIdx.x;

    // ---- W staging: 4608 items = 288 k-pairs x 16 n-quads; 9 items/thread.
    // Item: load W[k][n0..n0+3], W[k+1][n0..n0+3] (2x dwordx4, coalesced),
    // pack (k,k+1) bf16 pairs, 4x ds_write_b32 into B-fragment layout:
    // wf[((kk*4 + (n>>4))*64 + gq*16 + (n&15))*8 + (k&7)], kk=k>>5, gq=(k>>3)&3.
    #pragma unroll
    for (int it = 0; it < 9; ++it) {
        const int q  = tid + it * 512;
        const int kp = q >> 4;            // 0..287
        const int n0 = (q & 15) * 4;      // 0,4,..,60
        const int k  = kp * 2;
        f32x4 r0 = *reinterpret_cast<const f32x4*>(W + k * 64 + n0);
        f32x4 r1 = *reinterpret_cast<const f32x4*>(W + (k + 1) * 64 + n0);
        const int kk = k >> 5;
        const int gq = (k >> 3) & 3;
        const int e  = k & 7;
        #pragma unroll
        for (int i = 0; i < 4; ++i) {
            const int n = n0 + i;
            const unsigned pk = (unsigned)f2bf(r0[i]) | ((unsigned)f2bf(r1[i]) << 16);
            const int sidx = ((kk * 4 + (n >> 4)) * 64 + gq * 16 + (n & 15)) * 8 + e;
            *reinterpret_cast<unsigned*>(&wf[sidx]) = pk;
        }
    }
    __syncthreads();

    const int lane = tid & 63;
    const int wave = tid >> 6;
    const int m    = lane & 15;   // A row within wave tile / D col
    const int g    = lane >> 4;   // k-group

    // bias values this thread needs (n = nt*16 + m), loaded once
    float bv[4];
    #pragma unroll
    for (int nt = 0; nt < 4; ++nt) bv[nt] = bias[nt * 16 + m];

    const int block_c0 = blockIdx.x * ROWS_PER_BLOCK;

    // Issue the 4 gather loads (2 kk-fragments) for neighbor J into slot S.
    // Fragment floats: kk=2J -> [g*8, g*8+8); kk=2J+1 -> [32+g*8, 32+g*8+8).
    #define GISSUE(S, J)                                                        \
    {                                                                           \
        const int rj = nb[J];                                                   \
        const float* p = lv + (size_t)(rj < 0 ? 0 : rj) * CIN + g * 8;          \
        va[S][0] = *reinterpret_cast<const f32x4*>(p);                          \
        va[S][1] = *reinterpret_cast<const f32x4*>(p + 4);                      \
        va[S][2] = *reinterpret_cast<const f32x4*>(p + 32);                     \
        va[S][3] = *reinterpret_cast<const f32x4*>(p + 36);                     \
    }

    // Relu+cvt slot S, run the 8 MFMAs for neighbor J (kk = 2J, 2J+1).
    #define GPROC(S, J)                                                         \
    {                                                                           \
        short8 ae, ao;                                                          \
        _Pragma("unroll")                                                       \
        for (int e2 = 0; e2 < 4; ++e2) {                                        \
            ae[e2]     = (short)f2bf(fmaxf(va[S][0][e2], 0.f));                 \
            ae[e2 + 4] = (short)f2bf(fmaxf(va[S][1][e2], 0.f));                 \
            ao[e2]     = (short)f2bf(fmaxf(va[S][2][e2], 0.f));                 \
            ao[e2 + 4] = (short)f2bf(fmaxf(va[S][3][e2], 0.f));                 \
        }                                                                       \
        if (nb[J] < 0) { ae = (short8)0; ao = (short8)0; }                      \
        _Pragma("unroll")                                                       \
        for (int nt = 0; nt < 4; ++nt) {                                        \
            const short8 be = *reinterpret_cast<const short8*>(                 \
                &wf[(((2 * (J)) * 4 + nt) * 64 + lane) * 8]);                   \
            acc[nt] = __builtin_amdgcn_mfma_f32_16x16x32_bf16(ae, be, acc[nt], 0, 0, 0); \
        }                                                                       \
        _Pragma("unroll")                                                       \
        for (int nt = 0; nt < 4; ++nt) {                                        \
            const short8 bo = *reinterpret_cast<const short8*>(                 \
                &wf[(((2 * (J) + 1) * 4 + nt) * 64 + lane) * 8]);               \
            acc[nt] = __builtin_amdgcn_mfma_f32_16x16x32_bf16(ao, bo, acc[nt], 0, 0, 0); \
        }                                                                       \
    }

    #pragma unroll 1   // keep code size: one copy of the pipelined body
    for (int t = 0; t < G_TILES; ++t) {
        const int c0 = block_c0 + t * 128 + wave * 16;
        int c = c0 + m;
        if (c >= N_COARSE_C) c = N_COARSE_C - 1;   // clamp; stores masked below

        int nb[KNB];
        #pragma unroll
        for (int j = 0; j < KNB; ++j) nb[j] = nbr[c * KNB + j];

        f32x4 acc[4];
        #pragma unroll
        for (int nt = 0; nt < 4; ++nt) acc[nt] = (f32x4){0.f, 0.f, 0.f, 0.f};

        f32x4 va[4][4];   // pipeline slots; all indices compile-time constants

        GISSUE(0, 0) GISSUE(1, 1) GISSUE(2, 2) GISSUE(3, 3)
        GPROC(0, 0) GISSUE(0, 4)
        GPROC(1, 1) GISSUE(1, 5)
        GPROC(2, 2) GISSUE(2, 6)
        GPROC(3, 3) GISSUE(3, 7)
        GPROC(0, 4) GISSUE(0, 8)
        GPROC(1, 5)
        GPROC(2, 6)
        GPROC(3, 7)
        GPROC(0, 8)

        // Epilogue: D col = lane&15 (=m), D row = g*4 + r. Add bias, store f32.
        #pragma unroll
        for (int r = 0; r < 4; ++r) {
            const int cr = c0 + g * 4 + r;
            if (cr < N_COARSE_C) {
                #pragma unroll
                for (int nt = 0; nt < 4; ++nt) {
                    out[(size_t)cr * COUT + nt * 16 + m] = acc[nt][r] + bv[nt];
                }
            }
        }
    }
    #undef GISSUE
    #undef GPROC
}

extern "C" void kernel_launch(void* const* d_in, const int* in_sizes, int n_in,
                              void* d_out, int out_size, void* d_ws, size_t ws_size,
                              hipStream_t stream) {
    const float* lv   = (const float*)d_in[0];
    const int*   nbr  = (const int*)d_in[1];
    const float* W    = (const float*)d_in[2];
    const float* b    = (const float*)d_in[3];
    float* out = (float*)d_out;
    const int grid = (N_COARSE_C + ROWS_PER_BLOCK - 1) / ROWS_PER_BLOCK;  // 489
    relu_coarsen_mfma<<<grid, 512, 0, stream>>>(lv, nbr, W, b, out);
}